// Round 1
// 82.260 us; speedup vs baseline: 1.0209x; 1.0209x over previous
//
#include <hip/hip_runtime.h>

#define NSHAPES 32
#define BLOCK 256
#define PPT 4   // points per thread

// One rotated-rect SDF per shape, min over 32 shapes, per query point.
// Math per shape per point (13 VALU, sqrt deferred out of the loop):
//   rx = c*qx - s*qy - tx   (2 fma)
//   ry = s*qx + c*qy - ty   (2 fma)
//   dx = |rx| - radx        (1 sub w/ abs modifier)
//   dy = |ry| - rady        (1)
//   m  = max(dx,dy)         (1)
//   mx = max(dx,0), my = max(dy,0)  (2)
//   sq = mx*mx + my*my      (2: mul + fma)
//   minSq = min(minSq, sq); minIn = min(minIn, m)  (2)
// Final per point: minIn<0 ? minIn : sqrt(minSq)
//
// Round-1 changes vs 83.98us baseline:
//  - cosf/sinf -> __cosf/__sinf (v_cos/v_sin HW ops). Angles are in [0,0.1);
//    libm's Payne-Hanek path inflates whole-kernel VGPR budget + scratch.
//  - PPT 8->4: grid 1024->2048 blocks = 8 blocks/CU = 8 waves/SIMD (was 4),
//    __launch_bounds__(256,8) pins VGPR<=64 so occupancy is actually reached.
//  - guard-free template path (problem size divides block tile exactly).

template<bool GUARD>
__global__ __launch_bounds__(BLOCK, 8) void multi_rect_sdf_kernel(
    const float4* __restrict__ query4,   // n_f4 float4s = 2 points each
    const float*  __restrict__ trans,    // (32,2)
    const float*  __restrict__ rads,     // (32,2)
    const float*  __restrict__ angles,   // (32,)
    float2*       __restrict__ out2,     // n_f4 float2s
    int n_f4)
{
    __shared__ float4 A[NSHAPES];  // {c, s, tx, ty}
    __shared__ float2 B[NSHAPES];  // {radx, rady}

    const int t = threadIdx.x;
    if (t < NSHAPES) {
        float a = angles[t];
        // |a| < 0.1 in this problem: HW v_sin/v_cos are exact to ~1e-7 here,
        // and avoid the libm slow-path register/scratch cost.
        A[t] = make_float4(__cosf(a), __sinf(a), trans[2 * t], trans[2 * t + 1]);
        B[t] = make_float2(rads[2 * t], rads[2 * t + 1]);
    }
    __syncthreads();

    const int f4_per_block = BLOCK * PPT / 2;  // 512
    const int base = blockIdx.x * f4_per_block + t;

    // Coalesced loads: lane-contiguous float4s, PPT/2 strided batches.
    float qx[PPT], qy[PPT];
    #pragma unroll
    for (int j = 0; j < PPT / 2; ++j) {
        int idx = base + j * BLOCK;
        float4 q;
        if (!GUARD || idx < n_f4) q = query4[idx];
        else                      q = make_float4(0.f, 0.f, 0.f, 0.f);
        qx[2 * j]     = q.x; qy[2 * j]     = q.y;
        qx[2 * j + 1] = q.z; qy[2 * j + 1] = q.w;
    }

    float minSq[PPT], minIn[PPT];
    #pragma unroll
    for (int p = 0; p < PPT; ++p) { minSq[p] = 3.0e38f; minIn[p] = 0.0f; }

    #pragma unroll 4
    for (int k = 0; k < NSHAPES; ++k) {
        float4 a4 = A[k];   // broadcast ds_read_b128 (same addr all lanes)
        float2 b2 = B[k];   // broadcast ds_read_b64
        float c = a4.x, s = a4.y, tx = a4.z, ty = a4.w;
        float rdx = b2.x, rdy = b2.y;
        #pragma unroll
        for (int p = 0; p < PPT; ++p) {
            float rx = fmaf(c, qx[p], fmaf(-s, qy[p], -tx));
            float ry = fmaf(s, qx[p], fmaf(c, qy[p], -ty));
            float dx = fabsf(rx) - rdx;
            float dy = fabsf(ry) - rdy;
            float m  = fmaxf(dx, dy);
            float mx = fmaxf(dx, 0.0f);
            float my = fmaxf(dy, 0.0f);
            float sq = fmaf(mx, mx, my * my);
            minSq[p] = fminf(minSq[p], sq);
            minIn[p] = fminf(minIn[p], m);
        }
    }

    #pragma unroll
    for (int j = 0; j < PPT / 2; ++j) {
        int idx = base + j * BLOCK;
        if (!GUARD || idx < n_f4) {
            int p0 = 2 * j, p1 = 2 * j + 1;
            float r0 = (minIn[p0] < 0.0f) ? minIn[p0] : sqrtf(minSq[p0]);
            float r1 = (minIn[p1] < 0.0f) ? minIn[p1] : sqrtf(minSq[p1]);
            out2[idx] = make_float2(r0, r1);
        }
    }
}

extern "C" void kernel_launch(void* const* d_in, const int* in_sizes, int n_in,
                              void* d_out, int out_size, void* d_ws, size_t ws_size,
                              hipStream_t stream) {
    const float* query  = (const float*)d_in[0];
    const float* trans  = (const float*)d_in[1];
    const float* rads   = (const float*)d_in[2];
    const float* angles = (const float*)d_in[3];
    float* out = (float*)d_out;

    const int n_points = in_sizes[0] / 2;   // (N,2) -> N
    const int n_f4 = n_points / 2;          // 2 points per float4
    const int f4_per_block = BLOCK * PPT / 2;
    const int grid = (n_f4 + f4_per_block - 1) / f4_per_block;

    if (n_f4 % f4_per_block == 0) {
        multi_rect_sdf_kernel<false><<<grid, BLOCK, 0, stream>>>(
            (const float4*)query, trans, rads, angles, (float2*)out, n_f4);
    } else {
        multi_rect_sdf_kernel<true><<<grid, BLOCK, 0, stream>>>(
            (const float4*)query, trans, rads, angles, (float2*)out, n_f4);
    }
}